// Round 5
// baseline (15151.839 us; speedup 1.0000x reference)
//
#include <hip/hip_runtime.h>
#include <math.h>

#define BB 64
#define TT 256
#define HH 512
#define TH (TT*HH)
#define BTH (BB*TT*HH)

typedef __attribute__((ext_vector_type(8))) short short8;
typedef __attribute__((ext_vector_type(4))) float f32x4;

__device__ __forceinline__ unsigned short f32_bf16(float f) {
    unsigned int u = __float_as_uint(f);
    return (unsigned short)((u + 0x7fffu + ((u >> 16) & 1u)) >> 16);
}

// ---- one-time: weights fp32 -> bf16 in MFMA-fragment-major layout ----
// region: 2048x512, flat e = (nt*16+kc)*512 + lane*8 + j  <->  W[nt*16+(lane&15)][kc*32+(lane>>4)*8+j]
struct WConv {
    const float* src[10];
    int rs[10];
    int co[10];
    short* dst;
};
__global__ __launch_bounds__(256) void conv_w(WConv a) {
    const int rid = blockIdx.y;
    const int i = blockIdx.x * 256 + threadIdx.x;
    const int lane = i & 63;
    const int kc = (i >> 6) & 15;
    const int nt = i >> 10;
    const int n = nt * 16 + (lane & 15);
    const int kb = kc * 32 + (lane >> 4) * 8;
    const float* s = a.src[rid] + (size_t)n * a.rs[rid] + a.co[rid] + kb;
    float4 v0 = *(const float4*)s;
    float4 v1 = *(const float4*)(s + 4);
    short8 o;
    o[0]=f32_bf16(v0.x); o[1]=f32_bf16(v0.y); o[2]=f32_bf16(v0.z); o[3]=f32_bf16(v0.w);
    o[4]=f32_bf16(v1.x); o[5]=f32_bf16(v1.y); o[6]=f32_bf16(v1.z); o[7]=f32_bf16(v1.w);
    *(short8*)(a.dst + (size_t)rid * 1048576 + (size_t)i * 8) = o;
}

// ---- one-time: x fp32 -> bf16 fragment-major ----
struct XConv {
    const float* src[3];
    short* dst;
};
__global__ __launch_bounds__(256) void conv_x(XConv a) {
    const int l = blockIdx.y;
    const int i = blockIdx.x * 256 + threadIdx.x;
    const int lane = i & 63;
    const int kc = (i >> 6) & 15;
    const int btt = i >> 10;
    const int bt = btt & 3;
    const int t = btt >> 2;
    const int b = bt * 16 + (lane & 15);
    const int k = kc * 32 + (lane >> 4) * 8;
    const float* s = a.src[l] + ((size_t)b * TT + t) * HH + k;
    float4 v0 = *(const float4*)s;
    float4 v1 = *(const float4*)(s + 4);
    short8 o;
    o[0]=f32_bf16(v0.x); o[1]=f32_bf16(v0.y); o[2]=f32_bf16(v0.z); o[3]=f32_bf16(v0.w);
    o[4]=f32_bf16(v1.x); o[5]=f32_bf16(v1.y); o[6]=f32_bf16(v1.z); o[7]=f32_bf16(v1.w);
    *(short8*)(a.dst + (size_t)l * 8388608 + (size_t)i * 8) = o;
}

// ---- persistent, layer-parallel sequential kernel ----
// 192 blocks = 3 layers x 4 bt x 16 cb (32 output cols each); 256 thr = 4 waves (one per gate).
struct PersArgs {
    const short* wreg; const short* xreg; short* hreg;
    const float* dx; float* out; int* flags;
    const float* bih[3]; const float* bhh[3];
};

__global__ __launch_bounds__(256, 4) void persistent_kernel(PersArgs a) {
    const int bid = blockIdx.x;
    const int l  = bid >> 6;             // 0..2
    const int rr = bid & 63;
    const int cb = rr & 15;              // 0..15 (32 cols each)
    const int bt = rr >> 4;              // 0..3
    const int tid = threadIdx.x;
    const int lane = tid & 63;
    const int q = tid >> 6;              // gate
    const int r16 = lane & 15;
    const int b_lane = bt * 16 + r16;

    __shared__ float g[4][2][16][17];
    __shared__ unsigned short hstage[512];

    float c_reg[2] = {0.f, 0.f}, h_reg[2] = {0.f, 0.f};
    float eb[2][4];
    const int b_i = tid >> 4, c_i = tid & 15;   // epilogue coords (all 256 threads)
    const int ebrow = bt * 16 + b_i;
    #pragma unroll
    for (int sub = 0; sub < 2; ++sub) {
        const int ec = cb * 32 + sub * 16 + c_i;
        #pragma unroll
        for (int qq = 0; qq < 4; ++qq)
            eb[sub][qq] = a.bih[l][qq*512 + ec] + a.bhh[l][qq*512 + ec];
    }

    const int WX[3]  = {0, 3, 7};
    const int WTD[3] = {1, 5, 5};
    const int WBU[3] = {4, 4, 8};
    const int WHH[3] = {2, 6, 9};
    const size_t w0off = ((size_t)(q*32 + cb*2) * 16) * 512 + lane * 8;  // sub1: +8192
    const short* whh = a.wreg + (size_t)WHH[l]*1048576 + w0off;
    const short* wtd = a.wreg + (size_t)WTD[l]*1048576 + w0off;
    const short* wbu = a.wreg + (size_t)WBU[l]*1048576 + w0off;
    const short* wx  = a.wreg + (size_t)WX[l]*1048576  + w0off;
    const int haoff = bt * 8192 + lane * 8;      // + kc*512
    const short8 vz = {0,0,0,0,0,0,0,0};

    for (int t = 0; t < TT; ++t) {
        const int stage = t*3 + l;
        const float dbv = (l == 0) ? 1.f : a.dx[b_lane*768 + (l-1)*256 + t];
        const float dv  = (t == 0) ? 0.f : a.dx[b_lane*768 + l*256 + (t-1)];
        f32x4 acc0 = {0.f,0.f,0.f,0.f}, acc1 = {0.f,0.f,0.f,0.f};

        // ---- x segment: no dependency, runs before any poll (jitter absorber) ----
        {
            const bool nz = (l == 0) || (dbv != 0.f);
            const short* ap = a.xreg + (size_t)l*8388608 + (size_t)t*32768 + haoff;
            #pragma unroll
            for (int kc = 0; kc < 16; ++kc) {
                short8 av = *(const short8*)(ap + kc*512);
                av = nz ? av : vz;
                acc0 = __builtin_amdgcn_mfma_f32_16x16x32_bf16(av, *(const short8*)(wx + kc*512), acc0, 0, 0, 0);
                acc1 = __builtin_amdgcn_mfma_f32_16x16x32_bf16(av, *(const short8*)(wx + 8192 + kc*512), acc1, 0, 0, 0);
            }
        }

        // ---- t-1 dependencies (hh + td), one merged poll ----
        if (t > 0) {
            if (q == 0) {
                const int* f1 = a.flags + (((t-1)*3 + l)*4 + bt)*16;
                const int* f2 = (l < 2) ? a.flags + (((t-1)*3 + l + 1)*4 + bt)*16 : nullptr;
                for (;;) {
                    int v = 1;
                    if (lane < 16)
                        v = __hip_atomic_load(f1 + lane, __ATOMIC_RELAXED, __HIP_MEMORY_SCOPE_AGENT);
                    else if (lane < 32 && f2)
                        v = __hip_atomic_load(f2 + lane - 16, __ATOMIC_RELAXED, __HIP_MEMORY_SCOPE_AGENT);
                    if (__all(v != 0)) break;
                    __builtin_amdgcn_s_sleep(1);
                }
                __builtin_amdgcn_fence(__ATOMIC_ACQUIRE, "agent");
            }
            __syncthreads();
            {   // recurrent hh
                const short* ap = a.hreg + (size_t)(l*2 + ((t-1)&1))*32768 + haoff;
                #pragma unroll
                for (int kc = 0; kc < 16; ++kc) {
                    short8 av = *(const short8*)(ap + kc*512);
                    acc0 = __builtin_amdgcn_mfma_f32_16x16x32_bf16(av, *(const short8*)(whh + kc*512), acc0, 0, 0, 0);
                    acc1 = __builtin_amdgcn_mfma_f32_16x16x32_bf16(av, *(const short8*)(whh + 8192 + kc*512), acc1, 0, 0, 0);
                }
            }
            if (l < 2) {   // top-down
                const bool nz = dv != 0.f;
                const short* ap = a.hreg + (size_t)((l+1)*2 + ((t-1)&1))*32768 + haoff;
                #pragma unroll
                for (int kc = 0; kc < 16; ++kc) {
                    short8 av = *(const short8*)(ap + kc*512);
                    av = nz ? av : vz;
                    acc0 = __builtin_amdgcn_mfma_f32_16x16x32_bf16(av, *(const short8*)(wtd + kc*512), acc0, 0, 0, 0);
                    acc1 = __builtin_amdgcn_mfma_f32_16x16x32_bf16(av, *(const short8*)(wtd + 8192 + kc*512), acc1, 0, 0, 0);
                }
            }
        }

        // ---- same-t bottom-up dependency ----
        if (l > 0) {
            if (q == 0) {
                const int* f3 = a.flags + ((t*3 + l - 1)*4 + bt)*16;
                for (;;) {
                    int v = 1;
                    if (lane < 16)
                        v = __hip_atomic_load(f3 + lane, __ATOMIC_RELAXED, __HIP_MEMORY_SCOPE_AGENT);
                    if (__all(v != 0)) break;
                    __builtin_amdgcn_s_sleep(1);
                }
                __builtin_amdgcn_fence(__ATOMIC_ACQUIRE, "agent");
            }
            __syncthreads();
            const bool nz = dbv != 0.f;
            const short* ap = a.hreg + (size_t)((l-1)*2 + (t&1))*32768 + haoff;
            #pragma unroll
            for (int kc = 0; kc < 16; ++kc) {
                short8 av = *(const short8*)(ap + kc*512);
                av = nz ? av : vz;
                acc0 = __builtin_amdgcn_mfma_f32_16x16x32_bf16(av, *(const short8*)(wbu + kc*512), acc0, 0, 0, 0);
                acc1 = __builtin_amdgcn_mfma_f32_16x16x32_bf16(av, *(const short8*)(wbu + 8192 + kc*512), acc1, 0, 0, 0);
            }
        }

        // ---- gate exchange ----
        #pragma unroll
        for (int r = 0; r < 4; ++r) {
            g[q][0][(lane >> 4)*4 + r][r16] = acc0[r];
            g[q][1][(lane >> 4)*4 + r][r16] = acc1[r];
        }
        __syncthreads();

        // ---- cell epilogue: 256 threads, 2 cols each ----
        float hv[2];
        {
            const float db2 = (l == 0) ? 1.f : a.dx[ebrow*768 + (l-1)*256 + t];
            const float d2  = (t == 0) ? 0.f : a.dx[ebrow*768 + l*256 + (t-1)];
            const bool copy = (db2 + d2 == 0.f);
            #pragma unroll
            for (int sub = 0; sub < 2; ++sub) {
                float gi = g[0][sub][b_i][c_i] + eb[sub][0];
                float gf = g[1][sub][b_i][c_i] + eb[sub][1];
                float gg = g[2][sub][b_i][c_i] + eb[sub][2];
                float go = g[3][sub][b_i][c_i] + eb[sub][3];
                const float i_ = 1.f/(1.f + expf(-gi));
                const float f_ = 1.f/(1.f + expf(-gf));
                const float g_ = tanhf(gg);
                const float o_ = 1.f/(1.f + expf(-go));
                const float cc = c_reg[sub] * (1.f - d2);
                const float cn_ = f_*cc + i_*g_;
                const float hn_ = o_*tanhf(cn_);
                const float h = copy ? h_reg[sub] : hn_;
                c_reg[sub] = copy ? cc : cn_;
                h_reg[sub] = h;
                hv[sub] = h;
                hstage[b_i*32 + sub*16 + c_i] = f32_bf16(h);
            }
        }
        __syncthreads();

        // ---- pack h tile -> bf16 ring slot (contiguous 1KB region per block) ----
        {
            const int u = tid;
            const int bp = (u >> 2) & 15;
            const int cl = (u >> 6)*8 + ((2*u) & 7);
            unsigned int lo16 = hstage[bp*32 + cl];
            unsigned int hi16 = hstage[bp*32 + cl + 1];
            unsigned int pack = lo16 | (hi16 << 16);
            unsigned int* dst = (unsigned int*)(a.hreg + (size_t)(l*2 + (t&1))*32768)
                                + (bt*16 + cb)*256 + u;
            __hip_atomic_store(dst, pack, __ATOMIC_RELAXED, __HIP_MEMORY_SCOPE_AGENT);
        }
        __syncthreads();   // all pack stores drained before flag

        if (tid == 0)
            __hip_atomic_store(a.flags + ((stage*4 + bt)*16 + cb), 1,
                               __ATOMIC_RELEASE, __HIP_MEMORY_SCOPE_AGENT);

        // HBM output stores after the flag -> off the critical path
        #pragma unroll
        for (int sub = 0; sub < 2; ++sub)
            a.out[(size_t)l*BTH + (size_t)ebrow*TH + (size_t)t*HH + cb*32 + sub*16 + c_i] = hv[sub];
    }
}

extern "C" void kernel_launch(void* const* d_in, const int* in_sizes, int n_in,
                              void* d_out, int out_size, void* d_ws, size_t ws_size,
                              hipStream_t stream) {
    const float* x[3]    = {(const float*)d_in[0], (const float*)d_in[1], (const float*)d_in[2]};
    const float* dx      = (const float*)d_in[3];
    const float* W_ih[3] = {(const float*)d_in[4], (const float*)d_in[8],  (const float*)d_in[12]};
    const float* W_hh[3] = {(const float*)d_in[5], (const float*)d_in[9],  (const float*)d_in[13]};
    const float* b_ih[3] = {(const float*)d_in[6], (const float*)d_in[10], (const float*)d_in[14]};
    const float* b_hh[3] = {(const float*)d_in[7], (const float*)d_in[11], (const float*)d_in[15]};
    float* out = (float*)d_out;

    char* ws = (char*)d_ws;
    const size_t SZ_FLAGS = 196608;                 // 768*4*16 ints
    const size_t SZ_WREG  = 20971520;               // 10*2048*512 bf16
    const size_t SZ_XREG  = 50331648;               // 3*64*256*512 bf16
    int*   flags = (int*)ws;
    short* wreg  = (short*)(ws + SZ_FLAGS);
    short* xreg  = (short*)(ws + SZ_FLAGS + SZ_WREG);
    short* hreg  = (short*)(ws + SZ_FLAGS + SZ_WREG + SZ_XREG);  // 3*2*64*512 bf16

    hipMemsetAsync(flags, 0, SZ_FLAGS, stream);

    {
        WConv wa;
        const float* srcs[10] = {W_ih[0], W_ih[0], W_hh[0],
                                 W_ih[1], W_ih[1], W_ih[1], W_hh[1],
                                 W_ih[2], W_ih[2], W_hh[2]};
        const int rss[10] = {1024, 1024, 512, 1536, 1536, 1536, 512, 1024, 1024, 512};
        const int cos[10] = {0, 512, 0, 0, 512, 1024, 0, 0, 512, 0};
        for (int r = 0; r < 10; ++r) { wa.src[r] = srcs[r]; wa.rs[r] = rss[r]; wa.co[r] = cos[r]; }
        wa.dst = wreg;
        conv_w<<<dim3(512, 10), 256, 0, stream>>>(wa);
    }
    {
        XConv xa;
        xa.src[0] = x[0]; xa.src[1] = x[1]; xa.src[2] = x[2];
        xa.dst = xreg;
        conv_x<<<dim3(4096, 3), 256, 0, stream>>>(xa);
    }

    PersArgs pa;
    pa.wreg = wreg; pa.xreg = xreg; pa.hreg = hreg;
    pa.dx = dx; pa.out = out; pa.flags = flags;
    for (int l = 0; l < 3; ++l) { pa.bih[l] = b_ih[l]; pa.bhh[l] = b_hh[l]; }
    persistent_kernel<<<dim3(192), 256, 0, stream>>>(pa);
}

// Round 6
// 7106.433 us; speedup vs baseline: 2.1321x; 2.1321x over previous
//
#include <hip/hip_runtime.h>
#include <math.h>

#define BB 64
#define TT 256
#define HH 512
#define TH (TT*HH)
#define BTH (BB*TT*HH)

typedef __attribute__((ext_vector_type(8))) short short8;
typedef __attribute__((ext_vector_type(4))) float f32x4;

__device__ __forceinline__ unsigned short f32_bf16(float f) {
    unsigned int u = __float_as_uint(f);
    return (unsigned short)((u + 0x7fffu + ((u >> 16) & 1u)) >> 16);
}

// ---- one-time: weights fp32 -> bf16, register-resident layout ----
// Per layer l, block nb (16 hcols), wave (nt,kh), chunk slot scc = seg*8+cc:
// short8 at slab[l] + (((nb*8 + nt*2 + kh)*NCH + scc)*64 + lane)*8
// holds W_orig[q*512 + hcol][co + (cc*2+kh)*32 + (lane>>4)*8 + j]
// where hcol = nb*16 + nt*4 + ((lane&15)>>2), q = lane&3  (gate-interleaved cols)
struct WConv2 {
    const float* src[3][4];
    int rs[3][4];
    int co[3][4];
    int nch[3];
    int cnt[3];        // short8 count per layer
    unsigned int slab[3];     // short offset
    short* dst;
};
__global__ __launch_bounds__(256) void conv_w(WConv2 a) {
    const int l = blockIdx.y;
    const int i = blockIdx.x * 256 + threadIdx.x;
    if (i >= a.cnt[l]) return;
    const int NCH = a.nch[l];
    const int lane = i & 63;
    const int r = i >> 6;
    const int scc = r % NCH;
    const int wv = r / NCH;
    const int kh = wv & 1;
    const int nt = (wv >> 1) & 3;
    const int nb = wv >> 3;
    const int seg = scc >> 3;
    const int cc = scc & 7;
    const int hcol = nb*16 + nt*4 + ((lane & 15) >> 2);
    const int q = lane & 3;
    const int row = q*512 + hcol;
    const int k = a.co[l][seg] + (cc*2 + kh)*32 + (lane >> 4)*8;
    const float* s = a.src[l][seg] + (size_t)row * a.rs[l][seg] + k;
    float4 v0 = *(const float4*)s;
    float4 v1 = *(const float4*)(s + 4);
    short8 o;
    o[0]=f32_bf16(v0.x); o[1]=f32_bf16(v0.y); o[2]=f32_bf16(v0.z); o[3]=f32_bf16(v0.w);
    o[4]=f32_bf16(v1.x); o[5]=f32_bf16(v1.y); o[6]=f32_bf16(v1.z); o[7]=f32_bf16(v1.w);
    *(short8*)(a.dst + (size_t)a.slab[l] + (size_t)i * 8) = o;
}

// ---- one-time: x fp32 -> bf16 fragment-major (A-side) ----
// e = ((t*4+mt)*16 + kc)*512 + lane*8 + j <-> x[b=mt*16+(lane&15)][t][kc*32+(lane>>4)*8+j]
struct XConv {
    const float* src[3];
    short* dst;
};
__global__ __launch_bounds__(256) void conv_x(XConv a) {
    const int l = blockIdx.y;
    const int i = blockIdx.x * 256 + threadIdx.x;
    const int lane = i & 63;
    const int kc = (i >> 6) & 15;
    const int btt = i >> 10;
    const int bt = btt & 3;
    const int t = btt >> 2;
    const int b = bt * 16 + (lane & 15);
    const int k = kc * 32 + (lane >> 4) * 8;
    const float* s = a.src[l] + ((size_t)b * TT + t) * HH + k;
    float4 v0 = *(const float4*)s;
    float4 v1 = *(const float4*)(s + 4);
    short8 o;
    o[0]=f32_bf16(v0.x); o[1]=f32_bf16(v0.y); o[2]=f32_bf16(v0.z); o[3]=f32_bf16(v0.w);
    o[4]=f32_bf16(v1.x); o[5]=f32_bf16(v1.y); o[6]=f32_bf16(v1.z); o[7]=f32_bf16(v1.w);
    *(short8*)(a.dst + (size_t)l * 8388608 + (size_t)i * 8) = o;
}

struct PersArgs {
    const short* wreg; const short* xreg; short* hreg;
    const float* dx; float* out; int* flags;
    const float* bih[3]; const float* bhh[3];
};

// One MFMA segment: 8 chunks (this wave's kh-interleaved half of 512 K),
// 4 m-tiles. SB must be a compile-time literal (static w[] indexing).
#define SEG_MFMA(SB, ASRC, SCP)                                               \
    {                                                                          \
        const short* ap_ = (ASRC) + (size_t)lane * 8;                          \
        _Pragma("unroll")                                                      \
        for (int cc = 0; cc < 8; ++cc) {                                       \
            const int cis = cc*2 + kh;                                         \
            short8 av[4];                                                      \
            _Pragma("unroll")                                                  \
            for (int mt = 0; mt < 4; ++mt)                                     \
                av[mt] = *(const short8*)(ap_ + (size_t)(mt*16 + cis) * 512);  \
            _Pragma("unroll")                                                  \
            for (int mt = 0; mt < 4; ++mt) {                                   \
                short8 xa = ((SCP) == nullptr || (SCP)[mt] != 0.f) ? av[mt] : vz; \
                acc[mt] = __builtin_amdgcn_mfma_f32_16x16x32_bf16(             \
                    xa, w[(SB) + cc], acc[mt], 0, 0, 0);                       \
            }                                                                  \
        }                                                                      \
    }

template<int L>
__device__ __forceinline__ void run_layer(const PersArgs& a, int nb,
                                          float* gsh) {
    constexpr int NSEG = (L == 1) ? 4 : 3;
    constexpr int NCH  = NSEG * 8;            // chunks per wave (kh half)
    constexpr unsigned int WSLAB = (L == 0) ? 0u : ((L == 1) ? 3145728u : 7340032u);
    // gsh layout: [kh][nt][mt][row16][col17]
    #define GSH(khi, nti, mti, ri, ci) gsh[((((khi)*4 + (nti))*4 + (mti))*16 + (ri))*17 + (ci)]

    const int tid  = threadIdx.x;
    const int lane = tid & 63;
    const int wv   = tid >> 6;
    const int nt   = wv >> 1;
    const int kh   = wv & 1;
    const int r16  = lane & 15;
    const short8 vz = {0,0,0,0,0,0,0,0};

    // ---- load this wave's weight slice into registers (stays for all 256 t) ----
    short8 w[NCH];
    {
        const short* wb = a.wreg + WSLAB
            + ((size_t)((nb*8 + nt*2 + kh) * NCH)) * 512 + lane * 8;
        #pragma unroll
        for (int i = 0; i < NCH; ++i)
            w[i] = *(const short8*)(wb + (size_t)i * 512);
    }

    // ---- epilogue constants: thread owns (b = tid>>3, hcol pair = tid&7) ----
    const int eb_b = tid >> 3;
    const int ehp  = tid & 7;
    float bias[2][4];
    #pragma unroll
    for (int e = 0; e < 2; ++e) {
        const int ec = nb*16 + 2*ehp + e;
        #pragma unroll
        for (int q = 0; q < 4; ++q)
            bias[e][q] = a.bih[L][q*512 + ec] + a.bhh[L][q*512 + ec];
    }
    float c_reg[2] = {0.f, 0.f}, h_reg[2] = {0.f, 0.f};

    for (int t = 0; t < TT; ++t) {
        const int pprev = (t - 1) & 1, pcur = t & 1;
        // per-m-tile scales (b = mt*16 + r16)
        float dbv[4], dvv[4];
        #pragma unroll
        for (int mt = 0; mt < 4; ++mt) {
            const int b = mt*16 + r16;
            dbv[mt] = (L == 0) ? 1.f : a.dx[b*768 + (L-1)*256 + t];
            dvv[mt] = (t == 0) ? 0.f : a.dx[b*768 + L*256 + (t-1)];
        }
        f32x4 acc[4];
        #pragma unroll
        for (int mt = 0; mt < 4; ++mt) acc[mt] = (f32x4){0.f, 0.f, 0.f, 0.f};

        // ---- x segment: no dependency, absorbs jitter ----
        SEG_MFMA(0, a.xreg + (size_t)L*8388608 + (size_t)t*32768,
                 (L == 0) ? (const float*)nullptr : dbv);

        // ---- t-1 deps (hh + td), one merged poll ----
        if (t > 0) {
            if (wv == 0) {
                const int* f1 = a.flags + ((t-1)*3 + L)*32;
                for (;;) {
                    int v = 1;
                    if (lane < 32)
                        v = __hip_atomic_load(f1 + lane, __ATOMIC_RELAXED, __HIP_MEMORY_SCOPE_AGENT);
                    else if (L < 2)
                        v = __hip_atomic_load(f1 + 32 + lane - 32 + 32, __ATOMIC_RELAXED, __HIP_MEMORY_SCOPE_AGENT);
                    if (__all(v != 0)) break;
                    __builtin_amdgcn_s_sleep(1);
                }
                __builtin_amdgcn_fence(__ATOMIC_ACQUIRE, "agent");
            }
            __syncthreads();
            SEG_MFMA(8, a.hreg + (size_t)(L*2 + pprev)*32768, (const float*)nullptr);
            if (L < 2)
                SEG_MFMA(16, a.hreg + (size_t)((L+1)*2 + pprev)*32768, dvv);
        }

        // ---- same-t bottom-up dep ----
        if (L > 0) {
            if (wv == 0) {
                const int* f3 = a.flags + (t*3 + L - 1)*32;
                for (;;) {
                    int v = 1;
                    if (lane < 32)
                        v = __hip_atomic_load(f3 + lane, __ATOMIC_RELAXED, __HIP_MEMORY_SCOPE_AGENT);
                    if (__all(v != 0)) break;
                    __builtin_amdgcn_s_sleep(1);
                }
                __builtin_amdgcn_fence(__ATOMIC_ACQUIRE, "agent");
            }
            __syncthreads();
            SEG_MFMA(NCH - 8, a.hreg + (size_t)((L-1)*2 + pcur)*32768, dbv);
        }

        // ---- acc -> LDS exchange ----
        #pragma unroll
        for (int mt = 0; mt < 4; ++mt)
            #pragma unroll
            for (int r = 0; r < 4; ++r)
                GSH(kh, nt, mt, (lane >> 4)*4 + r, r16) = acc[mt][r];
        __syncthreads();

        // ---- cell epilogue: 512 threads x 2 hcols ----
        float hval[2];
        {
            const float db2 = (L == 0) ? 1.f : a.dx[eb_b*768 + (L-1)*256 + t];
            const float d2  = (t == 0) ? 0.f : a.dx[eb_b*768 + L*256 + (t-1)];
            const bool copy = (db2 + d2 == 0.f);
            const int mt = eb_b >> 4, row = eb_b & 15;
            #pragma unroll
            for (int e = 0; e < 2; ++e) {
                const int hl = 2*ehp + e;
                const int ntE = hl >> 2, cb = (hl & 3)*4;
                float G[4];
                #pragma unroll
                for (int q = 0; q < 4; ++q)
                    G[q] = GSH(0, ntE, mt, row, cb+q) + GSH(1, ntE, mt, row, cb+q) + bias[e][q];
                const float i_ = 1.f/(1.f + expf(-G[0]));
                const float f_ = 1.f/(1.f + expf(-G[1]));
                const float g_ = tanhf(G[2]);
                const float o_ = 1.f/(1.f + expf(-G[3]));
                const float cold = c_reg[e] * (1.f - d2);
                const float cn = f_*cold + i_*g_;
                const float hn = o_*tanhf(cn);
                hval[e] = copy ? h_reg[e] : hn;
                c_reg[e] = copy ? cold : cn;
                h_reg[e] = hval[e];
            }
            // pack 2 adjacent hcols -> one uint into hreg ring (fragment-major)
            unsigned int pack = (unsigned int)f32_bf16(hval[0])
                              | ((unsigned int)f32_bf16(hval[1]) << 16);
            const int k  = nb*16 + 2*ehp;
            const int kc = k >> 5, kk = k & 31;
            const int lhi = kk >> 3, j = kk & 7;
            unsigned int* dst = (unsigned int*)(a.hreg + (size_t)(L*2 + pcur)*32768)
                + ((((size_t)(mt*16 + kc))*64 + lhi*16 + row)*8 + j) / 2;
            __hip_atomic_store(dst, pack, __ATOMIC_RELAXED, __HIP_MEMORY_SCOPE_AGENT);
        }
        __syncthreads();   // drains all pack stores (waitcnt before barrier)

        if (tid == 0)
            __hip_atomic_store(a.flags + (t*3 + L)*32 + nb, 1,
                               __ATOMIC_RELEASE, __HIP_MEMORY_SCOPE_AGENT);

        // HBM output store after the flag -> off the critical path
        *(float2*)(a.out + (size_t)L*BTH + (size_t)eb_b*TH + (size_t)t*HH
                   + nb*16 + 2*ehp) = make_float2(hval[0], hval[1]);
    }
    #undef GSH
}

__global__ __launch_bounds__(512, 2) void persistent_kernel(PersArgs a) {
    __shared__ float gsh[2*4*4*16*17];
    const int bid = blockIdx.x;
    if (bid < 32)       run_layer<0>(a, bid, gsh);
    else if (bid < 64)  run_layer<1>(a, bid - 32, gsh);
    else                run_layer<2>(a, bid - 64, gsh);
}

extern "C" void kernel_launch(void* const* d_in, const int* in_sizes, int n_in,
                              void* d_out, int out_size, void* d_ws, size_t ws_size,
                              hipStream_t stream) {
    const float* x[3]    = {(const float*)d_in[0], (const float*)d_in[1], (const float*)d_in[2]};
    const float* dx      = (const float*)d_in[3];
    const float* W_ih[3] = {(const float*)d_in[4], (const float*)d_in[8],  (const float*)d_in[12]};
    const float* W_hh[3] = {(const float*)d_in[5], (const float*)d_in[9],  (const float*)d_in[13]};
    const float* b_ih[3] = {(const float*)d_in[6], (const float*)d_in[10], (const float*)d_in[14]};
    const float* b_hh[3] = {(const float*)d_in[7], (const float*)d_in[11], (const float*)d_in[15]};
    float* out = (float*)d_out;

    char* ws = (char*)d_ws;
    const size_t SZ_FLAGS = 98304;                  // 768*32 ints
    const size_t SZ_WREG  = 20971520;               // 10.5M bf16
    const size_t SZ_XREG  = 50331648;               // 3*64*256*512 bf16
    int*   flags = (int*)ws;
    short* wreg  = (short*)(ws + SZ_FLAGS);
    short* xreg  = (short*)(ws + SZ_FLAGS + SZ_WREG);
    short* hreg  = (short*)(ws + SZ_FLAGS + SZ_WREG + SZ_XREG);  // 3*2*64*512 bf16

    hipMemsetAsync(flags, 0, SZ_FLAGS, stream);

    {   // weight conversion: seg order per layer = [x, hh, td, bu]
        WConv2 wa;
        // L0: x, hh, td
        wa.src[0][0]=W_ih[0]; wa.rs[0][0]=1024; wa.co[0][0]=0;
        wa.src[0][1]=W_hh[0]; wa.rs[0][1]=512;  wa.co[0][1]=0;
        wa.src[0][2]=W_ih[0]; wa.rs[0][2]=1024; wa.co[0][2]=512;
        wa.src[0][3]=W_ih[0]; wa.rs[0][3]=1024; wa.co[0][3]=0;
        // L1: x, hh, td, bu
        wa.src[1][0]=W_ih[1]; wa.rs[1][0]=1536; wa.co[1][0]=0;
        wa.src[1][1]=W_hh[1]; wa.rs[1][1]=512;  wa.co[1][1]=0;
        wa.src[1][2]=W_ih[1]; wa.rs[1][2]=1536; wa.co[1][2]=1024;
        wa.src[1][3]=W_ih[1]; wa.rs[1][3]=1536; wa.co[1][3]=512;
        // L2: x, hh, bu
        wa.src[2][0]=W_ih[2]; wa.rs[2][0]=1024; wa.co[2][0]=0;
        wa.src[2][1]=W_hh[2]; wa.rs[2][1]=512;  wa.co[2][1]=0;
        wa.src[2][2]=W_ih[2]; wa.rs[2][2]=1024; wa.co[2][2]=512;
        wa.src[2][3]=W_ih[2]; wa.rs[2][3]=1024; wa.co[2][3]=0;
        wa.nch[0]=24; wa.nch[1]=32; wa.nch[2]=24;
        wa.cnt[0]=393216; wa.cnt[1]=524288; wa.cnt[2]=393216;
        wa.slab[0]=0; wa.slab[1]=3145728; wa.slab[2]=7340032;
        wa.dst = wreg;
        conv_w<<<dim3(2048, 3), 256, 0, stream>>>(wa);
    }
    {
        XConv xa;
        xa.src[0] = x[0]; xa.src[1] = x[1]; xa.src[2] = x[2];
        xa.dst = xreg;
        conv_x<<<dim3(4096, 3), 256, 0, stream>>>(xa);
    }

    PersArgs pa;
    pa.wreg = wreg; pa.xreg = xreg; pa.hreg = hreg;
    pa.dx = dx; pa.out = out; pa.flags = flags;
    for (int l = 0; l < 3; ++l) { pa.bih[l] = b_ih[l]; pa.bhh[l] = b_hh[l]; }
    persistent_kernel<<<dim3(96), 512, 0, stream>>>(pa);
}

// Round 7
// 6443.483 us; speedup vs baseline: 2.3515x; 1.1029x over previous
//
#include <hip/hip_runtime.h>
#include <math.h>

#define BB 64
#define TT 256
#define HH 512
#define TH (TT*HH)
#define BTH (BB*TT*HH)

typedef __attribute__((ext_vector_type(8))) short short8;
typedef __attribute__((ext_vector_type(4))) float f32x4;

__device__ __forceinline__ unsigned short f32_bf16(float f) {
    unsigned int u = __float_as_uint(f);
    return (unsigned short)((u + 0x7fffu + ((u >> 16) & 1u)) >> 16);
}

// coherent 16B fragment load: 2x u64 relaxed agent atomics (sc-bit loads
// bypass stale L1/L2 -> no acquire fence needed; same mechanism as the polls)
__device__ __forceinline__ short8 ld_coh(const short* p) {
    const unsigned long long* q = (const unsigned long long*)p;
    unsigned long long a = __hip_atomic_load(q,     __ATOMIC_RELAXED, __HIP_MEMORY_SCOPE_AGENT);
    unsigned long long b = __hip_atomic_load(q + 1, __ATOMIC_RELAXED, __HIP_MEMORY_SCOPE_AGENT);
    union { unsigned long long u[2]; short8 s; } r;
    r.u[0] = a; r.u[1] = b;
    return r.s;
}

// ---- one-time: weights fp32 -> bf16, register-resident layout ----
struct WConv2 {
    const float* src[3][4];
    int rs[3][4];
    int co[3][4];
    int nch[3];
    int cnt[3];
    unsigned int slab[3];
    short* dst;
};
__global__ __launch_bounds__(256) void conv_w(WConv2 a) {
    const int l = blockIdx.y;
    const int i = blockIdx.x * 256 + threadIdx.x;
    if (i >= a.cnt[l]) return;
    const int NCH = a.nch[l];
    const int lane = i & 63;
    const int r = i >> 6;
    const int scc = r % NCH;
    const int wv = r / NCH;
    const int kh = wv & 1;
    const int nt = (wv >> 1) & 3;
    const int nb = wv >> 3;
    const int seg = scc >> 3;
    const int cc = scc & 7;
    const int hcol = nb*16 + nt*4 + ((lane & 15) >> 2);
    const int q = lane & 3;
    const int row = q*512 + hcol;
    const int k = a.co[l][seg] + (cc*2 + kh)*32 + (lane >> 4)*8;
    const float* s = a.src[l][seg] + (size_t)row * a.rs[l][seg] + k;
    float4 v0 = *(const float4*)s;
    float4 v1 = *(const float4*)(s + 4);
    short8 o;
    o[0]=f32_bf16(v0.x); o[1]=f32_bf16(v0.y); o[2]=f32_bf16(v0.z); o[3]=f32_bf16(v0.w);
    o[4]=f32_bf16(v1.x); o[5]=f32_bf16(v1.y); o[6]=f32_bf16(v1.z); o[7]=f32_bf16(v1.w);
    *(short8*)(a.dst + (size_t)a.slab[l] + (size_t)i * 8) = o;
}

// ---- one-time: x fp32 -> bf16 fragment-major (A-side) ----
struct XConv {
    const float* src[3];
    short* dst;
};
__global__ __launch_bounds__(256) void conv_x(XConv a) {
    const int l = blockIdx.y;
    const int i = blockIdx.x * 256 + threadIdx.x;
    const int lane = i & 63;
    const int kc = (i >> 6) & 15;
    const int btt = i >> 10;
    const int bt = btt & 3;
    const int t = btt >> 2;
    const int b = bt * 16 + (lane & 15);
    const int k = kc * 32 + (lane >> 4) * 8;
    const float* s = a.src[l] + ((size_t)b * TT + t) * HH + k;
    float4 v0 = *(const float4*)s;
    float4 v1 = *(const float4*)(s + 4);
    short8 o;
    o[0]=f32_bf16(v0.x); o[1]=f32_bf16(v0.y); o[2]=f32_bf16(v0.z); o[3]=f32_bf16(v0.w);
    o[4]=f32_bf16(v1.x); o[5]=f32_bf16(v1.y); o[6]=f32_bf16(v1.z); o[7]=f32_bf16(v1.w);
    *(short8*)(a.dst + (size_t)l * 8388608 + (size_t)i * 8) = o;
}

struct PersArgs {
    const short* wreg; const short* xreg; short* hreg;
    const float* dx; float* out; int* flags;
    const float* bih[3]; const float* bhh[3];
};

// plain-cached A loads (x segment: read-only data, safe to cache)
#define SEG_MFMA_PLAIN(SB, ASRC, SCP)                                          \
    {                                                                          \
        const short* ap_ = (ASRC) + (size_t)lane * 8;                          \
        _Pragma("unroll")                                                      \
        for (int cc = 0; cc < 8; ++cc) {                                       \
            const int cis = cc*2 + kh;                                         \
            short8 av[4];                                                      \
            _Pragma("unroll")                                                  \
            for (int mt = 0; mt < 4; ++mt)                                     \
                av[mt] = *(const short8*)(ap_ + (size_t)(mt*16 + cis) * 512);  \
            _Pragma("unroll")                                                  \
            for (int mt = 0; mt < 4; ++mt) {                                   \
                short8 xa = ((SCP) == nullptr || (SCP)[mt] != 0.f) ? av[mt] : vz; \
                acc[mt] = __builtin_amdgcn_mfma_f32_16x16x32_bf16(             \
                    xa, w[(SB) + cc], acc[mt], 0, 0, 0);                       \
            }                                                                  \
        }                                                                      \
    }

// coherent A loads (hreg segments: written by other blocks this step)
#define SEG_MFMA_COH(SB, ASRC, SCP)                                            \
    {                                                                          \
        const short* ap_ = (ASRC) + (size_t)lane * 8;                          \
        _Pragma("unroll")                                                      \
        for (int cc = 0; cc < 8; ++cc) {                                       \
            const int cis = cc*2 + kh;                                         \
            short8 av[4];                                                      \
            _Pragma("unroll")                                                  \
            for (int mt = 0; mt < 4; ++mt)                                     \
                av[mt] = ld_coh(ap_ + (size_t)(mt*16 + cis) * 512);            \
            _Pragma("unroll")                                                  \
            for (int mt = 0; mt < 4; ++mt) {                                   \
                short8 xa = ((SCP) == nullptr || (SCP)[mt] != 0.f) ? av[mt] : vz; \
                acc[mt] = __builtin_amdgcn_mfma_f32_16x16x32_bf16(             \
                    xa, w[(SB) + cc], acc[mt], 0, 0, 0);                       \
            }                                                                  \
        }                                                                      \
    }

template<int L>
__device__ __forceinline__ void run_layer(const PersArgs& a, int nb,
                                          float* gsh) {
    constexpr int NSEG = (L == 1) ? 4 : 3;
    constexpr int NCH  = NSEG * 8;
    constexpr unsigned int WSLAB = (L == 0) ? 0u : ((L == 1) ? 3145728u : 7340032u);
    #define GSH(khi, nti, mti, ri, ci) gsh[((((khi)*4 + (nti))*4 + (mti))*16 + (ri))*17 + (ci)]

    const int tid  = threadIdx.x;
    const int lane = tid & 63;
    const int wv   = tid >> 6;
    const int nt   = wv >> 1;
    const int kh   = wv & 1;
    const int r16  = lane & 15;
    const short8 vz = {0,0,0,0,0,0,0,0};

    // weight slice -> registers, lives across all 256 timesteps
    short8 w[NCH];
    {
        const short* wb = a.wreg + WSLAB
            + ((size_t)((nb*8 + nt*2 + kh) * NCH)) * 512 + lane * 8;
        #pragma unroll
        for (int i = 0; i < NCH; ++i)
            w[i] = *(const short8*)(wb + (size_t)i * 512);
    }

    const int eb_b = tid >> 3;
    const int ehp  = tid & 7;
    float bias[2][4];
    #pragma unroll
    for (int e = 0; e < 2; ++e) {
        const int ec = nb*16 + 2*ehp + e;
        #pragma unroll
        for (int q = 0; q < 4; ++q)
            bias[e][q] = a.bih[L][q*512 + ec] + a.bhh[L][q*512 + ec];
    }
    float c_reg[2] = {0.f, 0.f}, h_reg[2] = {0.f, 0.f};

    for (int t = 0; t < TT; ++t) {
        const int pprev = (t - 1) & 1, pcur = t & 1;
        float dbv[4], dvv[4];
        #pragma unroll
        for (int mt = 0; mt < 4; ++mt) {
            const int b = mt*16 + r16;
            dbv[mt] = (L == 0) ? 1.f : a.dx[b*768 + (L-1)*256 + t];
            dvv[mt] = (t == 0) ? 0.f : a.dx[b*768 + L*256 + (t-1)];
        }
        f32x4 acc[4];
        #pragma unroll
        for (int mt = 0; mt < 4; ++mt) acc[mt] = (f32x4){0.f, 0.f, 0.f, 0.f};

        // ---- x segment: no dependency, runs before any poll ----
        SEG_MFMA_PLAIN(0, a.xreg + (size_t)L*8388608 + (size_t)t*32768,
                       (L == 0) ? (const float*)nullptr : dbv);

        // ---- t-1 deps (hh + td), one merged 64-lane poll; NO fence ----
        if (t > 0) {
            if (wv == 0) {
                const int* f1 = a.flags + ((t-1)*3 + L)*32;   // [0:32)=L, [32:64)=L+1
                const int nlim = (L < 2) ? 64 : 32;
                for (;;) {
                    int v = 1;
                    if (lane < nlim)
                        v = __hip_atomic_load(f1 + lane, __ATOMIC_RELAXED, __HIP_MEMORY_SCOPE_AGENT);
                    if (__all(v != 0)) break;
                    __builtin_amdgcn_s_sleep(1);
                }
            }
            __syncthreads();
            SEG_MFMA_COH(8, a.hreg + (size_t)(L*2 + pprev)*32768, (const float*)nullptr);
            if (L < 2)
                SEG_MFMA_COH(16, a.hreg + (size_t)((L+1)*2 + pprev)*32768, dvv);
        }

        // ---- same-t bottom-up dep; NO fence ----
        if (L > 0) {
            if (wv == 0) {
                const int* f3 = a.flags + (t*3 + L - 1)*32;
                for (;;) {
                    int v = 1;
                    if (lane < 32)
                        v = __hip_atomic_load(f3 + lane, __ATOMIC_RELAXED, __HIP_MEMORY_SCOPE_AGENT);
                    if (__all(v != 0)) break;
                    __builtin_amdgcn_s_sleep(1);
                }
            }
            __syncthreads();
            SEG_MFMA_COH(NCH - 8, a.hreg + (size_t)((L-1)*2 + pcur)*32768, dbv);
        }

        // ---- acc -> LDS exchange ----
        #pragma unroll
        for (int mt = 0; mt < 4; ++mt)
            #pragma unroll
            for (int r = 0; r < 4; ++r)
                GSH(kh, nt, mt, (lane >> 4)*4 + r, r16) = acc[mt][r];
        __syncthreads();

        // ---- cell epilogue: 512 threads x 2 hcols ----
        float hval[2];
        {
            const float db2 = (L == 0) ? 1.f : a.dx[eb_b*768 + (L-1)*256 + t];
            const float d2  = (t == 0) ? 0.f : a.dx[eb_b*768 + L*256 + (t-1)];
            const bool copy = (db2 + d2 == 0.f);
            const int mt = eb_b >> 4, row = eb_b & 15;
            #pragma unroll
            for (int e = 0; e < 2; ++e) {
                const int hl = 2*ehp + e;
                const int ntE = hl >> 2, cb = (hl & 3)*4;
                float G[4];
                #pragma unroll
                for (int q = 0; q < 4; ++q)
                    G[q] = GSH(0, ntE, mt, row, cb+q) + GSH(1, ntE, mt, row, cb+q) + bias[e][q];
                const float i_ = 1.f/(1.f + expf(-G[0]));
                const float f_ = 1.f/(1.f + expf(-G[1]));
                const float g_ = tanhf(G[2]);
                const float o_ = 1.f/(1.f + expf(-G[3]));
                const float cold = c_reg[e] * (1.f - d2);
                const float cn = f_*cold + i_*g_;
                const float hn = o_*tanhf(cn);
                hval[e] = copy ? h_reg[e] : hn;
                c_reg[e] = copy ? cold : cn;
                h_reg[e] = hval[e];
            }
            unsigned int pack = (unsigned int)f32_bf16(hval[0])
                              | ((unsigned int)f32_bf16(hval[1]) << 16);
            const int k  = nb*16 + 2*ehp;
            const int kc = k >> 5, kk = k & 31;
            const int lhi = kk >> 3, j = kk & 7;
            unsigned int* dst = (unsigned int*)(a.hreg + (size_t)(L*2 + pcur)*32768)
                + ((((size_t)(mt*16 + kc))*64 + lhi*16 + row)*8 + j) / 2;
            __hip_atomic_store(dst, pack, __ATOMIC_RELAXED, __HIP_MEMORY_SCOPE_AGENT);
        }
        __syncthreads();   // per-thread vmcnt drained before barrier -> stores visible

        if (tid == 0)      // relaxed: ordering via drained stores + barrier + ctrl dep
            __hip_atomic_store(a.flags + (t*3 + L)*32 + nb, 1,
                               __ATOMIC_RELAXED, __HIP_MEMORY_SCOPE_AGENT);

        // HBM output: nontemporal (never re-read; keep L2/IF$ clean), after flag
        {
            union { float f[2]; unsigned long long u; } pk;
            pk.f[0] = hval[0]; pk.f[1] = hval[1];
            __builtin_nontemporal_store(pk.u,
                (unsigned long long*)(a.out + (size_t)L*BTH + (size_t)eb_b*TH
                                      + (size_t)t*HH + nb*16 + 2*ehp));
        }
    }
    #undef GSH
}

__global__ __launch_bounds__(512, 2) void persistent_kernel(PersArgs a) {
    __shared__ float gsh[2*4*4*16*17];
    const int bid = blockIdx.x;
    if (bid < 32)       run_layer<0>(a, bid, gsh);
    else if (bid < 64)  run_layer<1>(a, bid - 32, gsh);
    else                run_layer<2>(a, bid - 64, gsh);
}

extern "C" void kernel_launch(void* const* d_in, const int* in_sizes, int n_in,
                              void* d_out, int out_size, void* d_ws, size_t ws_size,
                              hipStream_t stream) {
    const float* x[3]    = {(const float*)d_in[0], (const float*)d_in[1], (const float*)d_in[2]};
    const float* dx      = (const float*)d_in[3];
    const float* W_ih[3] = {(const float*)d_in[4], (const float*)d_in[8],  (const float*)d_in[12]};
    const float* W_hh[3] = {(const float*)d_in[5], (const float*)d_in[9],  (const float*)d_in[13]};
    const float* b_ih[3] = {(const float*)d_in[6], (const float*)d_in[10], (const float*)d_in[14]};
    const float* b_hh[3] = {(const float*)d_in[7], (const float*)d_in[11], (const float*)d_in[15]};
    float* out = (float*)d_out;

    char* ws = (char*)d_ws;
    const size_t SZ_FLAGS = 98304;                  // 768*32 ints
    const size_t SZ_WREG  = 20971520;
    const size_t SZ_XREG  = 50331648;
    int*   flags = (int*)ws;
    short* wreg  = (short*)(ws + SZ_FLAGS);
    short* xreg  = (short*)(ws + SZ_FLAGS + SZ_WREG);
    short* hreg  = (short*)(ws + SZ_FLAGS + SZ_WREG + SZ_XREG);

    hipMemsetAsync(flags, 0, SZ_FLAGS, stream);

    {   // weight conversion: seg order per layer = [x, hh, td, bu]
        WConv2 wa;
        wa.src[0][0]=W_ih[0]; wa.rs[0][0]=1024; wa.co[0][0]=0;
        wa.src[0][1]=W_hh[0]; wa.rs[0][1]=512;  wa.co[0][1]=0;
        wa.src[0][2]=W_ih[0]; wa.rs[0][2]=1024; wa.co[0][2]=512;
        wa.src[0][3]=W_ih[0]; wa.rs[0][3]=1024; wa.co[0][3]=0;
        wa.src[1][0]=W_ih[1]; wa.rs[1][0]=1536; wa.co[1][0]=0;
        wa.src[1][1]=W_hh[1]; wa.rs[1][1]=512;  wa.co[1][1]=0;
        wa.src[1][2]=W_ih[1]; wa.rs[1][2]=1536; wa.co[1][2]=1024;
        wa.src[1][3]=W_ih[1]; wa.rs[1][3]=1536; wa.co[1][3]=512;
        wa.src[2][0]=W_ih[2]; wa.rs[2][0]=1024; wa.co[2][0]=0;
        wa.src[2][1]=W_hh[2]; wa.rs[2][1]=512;  wa.co[2][1]=0;
        wa.src[2][2]=W_ih[2]; wa.rs[2][2]=1024; wa.co[2][2]=512;
        wa.src[2][3]=W_ih[2]; wa.rs[2][3]=1024; wa.co[2][3]=0;
        wa.nch[0]=24; wa.nch[1]=32; wa.nch[2]=24;
        wa.cnt[0]=393216; wa.cnt[1]=524288; wa.cnt[2]=393216;
        wa.slab[0]=0; wa.slab[1]=3145728; wa.slab[2]=7340032;
        wa.dst = wreg;
        conv_w<<<dim3(2048, 3), 256, 0, stream>>>(wa);
    }
    {
        XConv xa;
        xa.src[0] = x[0]; xa.src[1] = x[1]; xa.src[2] = x[2];
        xa.dst = xreg;
        conv_x<<<dim3(4096, 3), 256, 0, stream>>>(xa);
    }

    PersArgs pa;
    pa.wreg = wreg; pa.xreg = xreg; pa.hreg = hreg;
    pa.dx = dx; pa.out = out; pa.flags = flags;
    for (int l = 0; l < 3; ++l) { pa.bih[l] = b_ih[l]; pa.bhh[l] = b_hh[l]; }
    persistent_kernel<<<dim3(96), 512, 0, stream>>>(pa);
}

// Round 8
// 4789.251 us; speedup vs baseline: 3.1637x; 1.3454x over previous
//
#include <hip/hip_runtime.h>
#include <math.h>

#define BB 64
#define TT 256
#define HH 512
#define TH (TT*HH)
#define BTH (BB*TT*HH)

typedef __attribute__((ext_vector_type(8))) short short8;
typedef __attribute__((ext_vector_type(4))) float f32x4;

__device__ __forceinline__ unsigned short f32_bf16(float f) {
    unsigned int u = __float_as_uint(f);
    return (unsigned short)((u + 0x7fffu + ((u >> 16) & 1u)) >> 16);
}

// coherent 16B fragment load: 2x u64 relaxed agent atomics (sc-bit loads
// bypass stale L1/L2; same mechanism as the flag polls)
__device__ __forceinline__ short8 ld_coh(const short* p) {
    const unsigned long long* q = (const unsigned long long*)p;
    unsigned long long a = __hip_atomic_load(q,     __ATOMIC_RELAXED, __HIP_MEMORY_SCOPE_AGENT);
    unsigned long long b = __hip_atomic_load(q + 1, __ATOMIC_RELAXED, __HIP_MEMORY_SCOPE_AGENT);
    union { unsigned long long u[2]; short8 s; } r;
    r.u[0] = a; r.u[1] = b;
    return r.s;
}

// ---- one-time: weights fp32 -> bf16, register-resident layout ----
struct WConv2 {
    const float* src[3][4];
    int rs[3][4];
    int co[3][4];
    int nch[3];
    int cnt[3];
    unsigned int slab[3];
    short* dst;
};
__global__ __launch_bounds__(256) void conv_w(WConv2 a) {
    const int l = blockIdx.y;
    const int i = blockIdx.x * 256 + threadIdx.x;
    if (i >= a.cnt[l]) return;
    const int NCH = a.nch[l];
    const int lane = i & 63;
    const int r = i >> 6;
    const int scc = r % NCH;
    const int wv = r / NCH;
    const int kh = wv & 1;
    const int nt = (wv >> 1) & 3;
    const int nb = wv >> 3;
    const int seg = scc >> 3;
    const int cc = scc & 7;
    const int hcol = nb*16 + nt*4 + ((lane & 15) >> 2);
    const int q = lane & 3;
    const int row = q*512 + hcol;
    const int k = a.co[l][seg] + (cc*2 + kh)*32 + (lane >> 4)*8;
    const float* s = a.src[l][seg] + (size_t)row * a.rs[l][seg] + k;
    float4 v0 = *(const float4*)s;
    float4 v1 = *(const float4*)(s + 4);
    short8 o;
    o[0]=f32_bf16(v0.x); o[1]=f32_bf16(v0.y); o[2]=f32_bf16(v0.z); o[3]=f32_bf16(v0.w);
    o[4]=f32_bf16(v1.x); o[5]=f32_bf16(v1.y); o[6]=f32_bf16(v1.z); o[7]=f32_bf16(v1.w);
    *(short8*)(a.dst + (size_t)a.slab[l] + (size_t)i * 8) = o;
}

// ---- one-time: x fp32 -> bf16 fragment-major (A-side) ----
struct XConv {
    const float* src[3];
    short* dst;
};
__global__ __launch_bounds__(256) void conv_x(XConv a) {
    const int l = blockIdx.y;
    const int i = blockIdx.x * 256 + threadIdx.x;
    const int lane = i & 63;
    const int kc = (i >> 6) & 15;
    const int btt = i >> 10;
    const int bt = btt & 3;
    const int t = btt >> 2;
    const int b = bt * 16 + (lane & 15);
    const int k = kc * 32 + (lane >> 4) * 8;
    const float* s = a.src[l] + ((size_t)b * TT + t) * HH + k;
    float4 v0 = *(const float4*)s;
    float4 v1 = *(const float4*)(s + 4);
    short8 o;
    o[0]=f32_bf16(v0.x); o[1]=f32_bf16(v0.y); o[2]=f32_bf16(v0.z); o[3]=f32_bf16(v0.w);
    o[4]=f32_bf16(v1.x); o[5]=f32_bf16(v1.y); o[6]=f32_bf16(v1.z); o[7]=f32_bf16(v1.w);
    *(short8*)(a.dst + (size_t)l * 8388608 + (size_t)i * 8) = o;
}

struct PersArgs {
    const short* wreg; const short* xreg; short* hreg;
    const float* dx; float* out; int* flags;
    const float* bih[3]; const float* bhh[3];
};

// plain-cached A loads (x segment)
#define SEG_MFMA_PLAIN(SB, ASRC, SCP)                                          \
    {                                                                          \
        const short* ap_ = (ASRC) + (size_t)lane * 8;                          \
        _Pragma("unroll")                                                      \
        for (int cc = 0; cc < 8; ++cc) {                                       \
            const int cis = cc*2 + kh;                                         \
            short8 av[4];                                                      \
            _Pragma("unroll")                                                  \
            for (int mt = 0; mt < 4; ++mt)                                     \
                av[mt] = *(const short8*)(ap_ + (size_t)(mt*16 + cis) * 512);  \
            _Pragma("unroll")                                                  \
            for (int mt = 0; mt < 4; ++mt) {                                   \
                short8 xa = ((SCP) == nullptr || (SCP)[mt] != 0.f) ? av[mt] : vz; \
                acc[mt] = __builtin_amdgcn_mfma_f32_16x16x32_bf16(             \
                    xa, w[(SB) + cc], acc[mt], 0, 0, 0);                       \
            }                                                                  \
        }                                                                      \
    }

// coherent A loads, 2-deep software pipeline (issue cc+1 before consuming cc)
#define SEG_MFMA_COH2(SB, ASRC, SCP)                                           \
    {                                                                          \
        const short* ap_ = (ASRC) + (size_t)lane * 8;                          \
        short8 curv[4], nxtv[4];                                               \
        _Pragma("unroll")                                                      \
        for (int mt = 0; mt < 4; ++mt)                                         \
            curv[mt] = ld_coh(ap_ + (size_t)(mt*16 + kh) * 512);               \
        _Pragma("unroll")                                                      \
        for (int cc = 0; cc < 8; ++cc) {                                       \
            if (cc < 7) {                                                      \
                const int cis = (cc+1)*2 + kh;                                 \
                _Pragma("unroll")                                              \
                for (int mt = 0; mt < 4; ++mt)                                 \
                    nxtv[mt] = ld_coh(ap_ + (size_t)(mt*16 + cis) * 512);      \
            }                                                                  \
            _Pragma("unroll")                                                  \
            for (int mt = 0; mt < 4; ++mt) {                                   \
                short8 xa = ((SCP) == nullptr || (SCP)[mt] != 0.f) ? curv[mt] : vz; \
                acc[mt] = __builtin_amdgcn_mfma_f32_16x16x32_bf16(             \
                    xa, w[(SB) + cc], acc[mt], 0, 0, 0);                       \
            }                                                                  \
            _Pragma("unroll")                                                  \
            for (int mt = 0; mt < 4; ++mt) curv[mt] = nxtv[mt];                \
        }                                                                      \
    }

template<int L>
__device__ __forceinline__ void run_layer(const PersArgs& a, int nb,
                                          float* gsh) {
    constexpr int NSEG = (L == 1) ? 4 : 3;
    constexpr int NCH  = NSEG * 8;
    constexpr unsigned int WSLAB = (L == 0) ? 0u : ((L == 1) ? 3145728u : 7340032u);
    #define GSH(khi, nti, mti, ri, ci) gsh[((((khi)*4 + (nti))*4 + (mti))*16 + (ri))*17 + (ci)]

    const int tid  = threadIdx.x;
    const int lane = tid & 63;
    const int wv   = tid >> 6;
    const int nt   = wv >> 1;
    const int kh   = wv & 1;
    const int r16  = lane & 15;
    const short8 vz = {0,0,0,0,0,0,0,0};

    // weight slice -> registers, lives across all 256 timesteps
    short8 w[NCH];
    {
        const short* wb = a.wreg + WSLAB
            + ((size_t)((nb*8 + nt*2 + kh) * NCH)) * 512 + lane * 8;
        #pragma unroll
        for (int i = 0; i < NCH; ++i)
            w[i] = *(const short8*)(wb + (size_t)i * 512);
    }

    const int eb_b = tid >> 3;
    const int ehp  = tid & 7;
    float bias[2][4];
    #pragma unroll
    for (int e = 0; e < 2; ++e) {
        const int ec = nb*16 + 2*ehp + e;
        #pragma unroll
        for (int q = 0; q < 4; ++q)
            bias[e][q] = a.bih[L][q*512 + ec] + a.bhh[L][q*512 + ec];
    }
    float c_reg[2] = {0.f, 0.f}, h_reg[2] = {0.f, 0.f};
    float hprev[2] = {0.f, 0.f};   // deferred out-store values (stage t-1)

    // wave0 32-lane poll on one stage's flag group; barrier releases block
    auto poll32 = [&](int st) {
        if (wv == 0) {
            const int* f = a.flags + st*32;
            for (;;) {
                int v = 1;
                if (lane < 32)
                    v = __hip_atomic_load(f + lane, __ATOMIC_RELAXED, __HIP_MEMORY_SCOPE_AGENT);
                if (__all(v != 0)) break;
                __builtin_amdgcn_s_sleep(1);
            }
        }
        __syncthreads();
    };

    for (int t = 0; t < TT; ++t) {
        const int pprev = (t - 1) & 1, pcur = t & 1;
        float dbv[4], dvv[4];
        #pragma unroll
        for (int mt = 0; mt < 4; ++mt) {
            const int b = mt*16 + r16;
            dbv[mt] = (L == 0) ? 1.f : a.dx[b*768 + (L-1)*256 + t];
            dvv[mt] = (t == 0) ? 0.f : a.dx[b*768 + L*256 + (t-1)];
        }
        f32x4 acc[4];
        #pragma unroll
        for (int mt = 0; mt < 4; ++mt) acc[mt] = (f32x4){0.f, 0.f, 0.f, 0.f};

        // ---- x segment: no dependency, runs before any poll ----
        SEG_MFMA_PLAIN(0, a.xreg + (size_t)L*8388608 + (size_t)t*32768,
                       (L == 0) ? (const float*)nullptr : dbv);

        if (t > 0) {
            // ---- hh: 2-links-stale dependency, poll first (usually instant) ----
            poll32((t-1)*3 + L);
            // deferred HBM out-store of stage t-1: acks overlap the hh loads,
            // NOT the polls (keeps store acks out of the poll-waitcnt FIFO)
            {
                union { float f[2]; unsigned long long u; } pk;
                pk.f[0] = hprev[0]; pk.f[1] = hprev[1];
                __builtin_nontemporal_store(pk.u,
                    (unsigned long long*)(a.out + (size_t)L*BTH + (size_t)eb_b*TH
                                          + (size_t)(t-1)*HH + nb*16 + 2*ehp));
            }
            SEG_MFMA_COH2(8, a.hreg + (size_t)(L*2 + pprev)*32768, (const float*)nullptr);
            // ---- td: 1-link-fresh, poll after hh work is done ----
            if (L < 2) {
                poll32((t-1)*3 + L + 1);
                SEG_MFMA_COH2(16, a.hreg + (size_t)((L+1)*2 + pprev)*32768, dvv);
            }
        }
        // ---- bu: freshest (same-t), last ----
        if (L > 0) {
            poll32(t*3 + L - 1);
            SEG_MFMA_COH2(NCH - 8, a.hreg + (size_t)((L-1)*2 + pcur)*32768, dbv);
        }

        // ---- acc -> LDS exchange ----
        #pragma unroll
        for (int mt = 0; mt < 4; ++mt)
            #pragma unroll
            for (int r = 0; r < 4; ++r)
                GSH(kh, nt, mt, (lane >> 4)*4 + r, r16) = acc[mt][r];
        __syncthreads();

        // ---- cell epilogue: 512 threads x 2 hcols ----
        float hval[2];
        {
            const float db2 = (L == 0) ? 1.f : a.dx[eb_b*768 + (L-1)*256 + t];
            const float d2  = (t == 0) ? 0.f : a.dx[eb_b*768 + L*256 + (t-1)];
            const bool copy = (db2 + d2 == 0.f);
            const int mt = eb_b >> 4, row = eb_b & 15;
            #pragma unroll
            for (int e = 0; e < 2; ++e) {
                const int hl = 2*ehp + e;
                const int ntE = hl >> 2, cb = (hl & 3)*4;
                float G[4];
                #pragma unroll
                for (int q = 0; q < 4; ++q)
                    G[q] = GSH(0, ntE, mt, row, cb+q) + GSH(1, ntE, mt, row, cb+q) + bias[e][q];
                const float i_ = 1.f/(1.f + expf(-G[0]));
                const float f_ = 1.f/(1.f + expf(-G[1]));
                const float g_ = tanhf(G[2]);
                const float o_ = 1.f/(1.f + expf(-G[3]));
                const float cold = c_reg[e] * (1.f - d2);
                const float cn = f_*cold + i_*g_;
                const float hn = o_*tanhf(cn);
                hval[e] = copy ? h_reg[e] : hn;
                c_reg[e] = copy ? cold : cn;
                h_reg[e] = hval[e];
            }
            unsigned int pack = (unsigned int)f32_bf16(hval[0])
                              | ((unsigned int)f32_bf16(hval[1]) << 16);
            const int k  = nb*16 + 2*ehp;
            const int kc = k >> 5, kk = k & 31;
            const int lhi = kk >> 3, j = kk & 7;
            unsigned int* dst = (unsigned int*)(a.hreg + (size_t)(L*2 + pcur)*32768)
                + ((((size_t)(mt*16 + kc))*64 + lhi*16 + row)*8 + j) / 2;
            __hip_atomic_store(dst, pack, __ATOMIC_RELAXED, __HIP_MEMORY_SCOPE_AGENT);
        }
        __syncthreads();   // per-thread vmcnt drained before barrier -> stores visible

        if (tid == 0)      // relaxed: ordering via drained stores + barrier + ctrl dep
            __hip_atomic_store(a.flags + (t*3 + L)*32 + nb, 1,
                               __ATOMIC_RELAXED, __HIP_MEMORY_SCOPE_AGENT);

        hprev[0] = hval[0]; hprev[1] = hval[1];
    }
    // flush final timestep's out-store
    {
        union { float f[2]; unsigned long long u; } pk;
        pk.f[0] = hprev[0]; pk.f[1] = hprev[1];
        __builtin_nontemporal_store(pk.u,
            (unsigned long long*)(a.out + (size_t)L*BTH + (size_t)eb_b*TH
                                  + (size_t)(TT-1)*HH + nb*16 + 2*ehp));
    }
    #undef GSH
}

__global__ __launch_bounds__(512, 2) void persistent_kernel(PersArgs a) {
    __shared__ float gsh[2*4*4*16*17];
    const int bid = blockIdx.x;
    if (bid < 32)       run_layer<0>(a, bid, gsh);
    else if (bid < 64)  run_layer<1>(a, bid - 32, gsh);
    else                run_layer<2>(a, bid - 64, gsh);
}

extern "C" void kernel_launch(void* const* d_in, const int* in_sizes, int n_in,
                              void* d_out, int out_size, void* d_ws, size_t ws_size,
                              hipStream_t stream) {
    const float* x[3]    = {(const float*)d_in[0], (const float*)d_in[1], (const float*)d_in[2]};
    const float* dx      = (const float*)d_in[3];
    const float* W_ih[3] = {(const float*)d_in[4], (const float*)d_in[8],  (const float*)d_in[12]};
    const float* W_hh[3] = {(const float*)d_in[5], (const float*)d_in[9],  (const float*)d_in[13]};
    const float* b_ih[3] = {(const float*)d_in[6], (const float*)d_in[10], (const float*)d_in[14]};
    const float* b_hh[3] = {(const float*)d_in[7], (const float*)d_in[11], (const float*)d_in[15]};
    float* out = (float*)d_out;

    char* ws = (char*)d_ws;
    const size_t SZ_FLAGS = 98304;                  // 768*32 ints
    const size_t SZ_WREG  = 20971520;
    const size_t SZ_XREG  = 50331648;
    int*   flags = (int*)ws;
    short* wreg  = (short*)(ws + SZ_FLAGS);
    short* xreg  = (short*)(ws + SZ_FLAGS + SZ_WREG);
    short* hreg  = (short*)(ws + SZ_FLAGS + SZ_WREG + SZ_XREG);

    hipMemsetAsync(flags, 0, SZ_FLAGS, stream);

    {   // weight conversion: seg order per layer = [x, hh, td, bu]
        WConv2 wa;
        wa.src[0][0]=W_ih[0]; wa.rs[0][0]=1024; wa.co[0][0]=0;
        wa.src[0][1]=W_hh[0]; wa.rs[0][1]=512;  wa.co[0][1]=0;
        wa.src[0][2]=W_ih[0]; wa.rs[0][2]=1024; wa.co[0][2]=512;
        wa.src[0][3]=W_ih[0]; wa.rs[0][3]=1024; wa.co[0][3]=0;
        wa.src[1][0]=W_ih[1]; wa.rs[1][0]=1536; wa.co[1][0]=0;
        wa.src[1][1]=W_hh[1]; wa.rs[1][1]=512;  wa.co[1][1]=0;
        wa.src[1][2]=W_ih[1]; wa.rs[1][2]=1536; wa.co[1][2]=1024;
        wa.src[1][3]=W_ih[1]; wa.rs[1][3]=1536; wa.co[1][3]=512;
        wa.src[2][0]=W_ih[2]; wa.rs[2][0]=1024; wa.co[2][0]=0;
        wa.src[2][1]=W_hh[2]; wa.rs[2][1]=512;  wa.co[2][1]=0;
        wa.src[2][2]=W_ih[2]; wa.rs[2][2]=1024; wa.co[2][2]=512;
        wa.src[2][3]=W_ih[2]; wa.rs[2][3]=1024; wa.co[2][3]=0;
        wa.nch[0]=24; wa.nch[1]=32; wa.nch[2]=24;
        wa.cnt[0]=393216; wa.cnt[1]=524288; wa.cnt[2]=393216;
        wa.slab[0]=0; wa.slab[1]=3145728; wa.slab[2]=7340032;
        wa.dst = wreg;
        conv_w<<<dim3(2048, 3), 256, 0, stream>>>(wa);
    }
    {
        XConv xa;
        xa.src[0] = x[0]; xa.src[1] = x[1]; xa.src[2] = x[2];
        xa.dst = xreg;
        conv_x<<<dim3(4096, 3), 256, 0, stream>>>(xa);
    }

    PersArgs pa;
    pa.wreg = wreg; pa.xreg = xreg; pa.hreg = hreg;
    pa.dx = dx; pa.out = out; pa.flags = flags;
    for (int l = 0; l < 3; ++l) { pa.bih[l] = b_ih[l]; pa.bhh[l] = b_hh[l]; }
    persistent_kernel<<<dim3(96), 512, 0, stream>>>(pa);
}